// Round 11
// baseline (352.819 us; speedup 1.0000x reference)
//
#include <hip/hip_runtime.h>
#include <hip/hip_bf16.h>

// ---------------------------------------------------------------------------
// AlsoDecoder, folded + fp16 MFMA, edges COUNTING-SORTED by col:
//   S[p] = feats[p]@W_f - pcd[p]@W_p + b_in   (MFMA prep kernel, fp16 table)
//   sort edges by col  ->  S gathers become L1/L2-broadcast hits
//   x1 = S[col] + also_pts[row]@W_p           (Q rebuilt per edge)
//   y  = relu(x1) @ W1                        (mfma 16x16x32 f16, swapped)
//   h2 = relu(y + b1); logits = h2 @ (W2@W_out) + folded bias
//   probs = sigmoid(logit diff); written to ORIGINAL edge slot
// ---------------------------------------------------------------------------

typedef _Float16 half8 __attribute__((ext_vector_type(8)));
typedef _Float16 half2v __attribute__((ext_vector_type(2)));
typedef __fp16   fp16x2 __attribute__((ext_vector_type(2)));
typedef __attribute__((ext_vector_type(4))) float f32x4;

union U84h { uint4 u; half8 h; };
union UPH  { half2v h; fp16x2 f; int i; unsigned u; };

__device__ __forceinline__ half2v cvt2h(float a, float b) {
    UPH t;
    t.f = __builtin_amdgcn_cvt_pkrtz(a, b);
    return t.h;
}

__device__ __forceinline__ half8 relu8(half8 v) {
    half8 z;
#pragma unroll
    for (int i = 0; i < 8; ++i) z[i] = (_Float16)0.f;
    return __builtin_elementwise_max(v, z);
}

// ---------------- prep: pack weights --------------------------------------
__global__ __launch_bounds__(256) void pack_fold(
    const float* __restrict__ w1, const float* __restrict__ w_in,
    const float* __restrict__ b1, const float* __restrict__ w2,
    const float* __restrict__ w_out, const float* __restrict__ b2,
    const float* __restrict__ b_out,
    _Float16* __restrict__ w1f, _Float16* __restrict__ wAf,
    _Float16* __restrict__ wpf, _Float16* __restrict__ w0h,
    _Float16* __restrict__ w1h, _Float16* __restrict__ b1h,
    float* __restrict__ bf) {
    int t = blockIdx.x * 256 + threadIdx.x;
    if (t < 4096) {
        int f = t >> 9, lane = (t >> 3) & 63, j = t & 7;
        int ntile = f >> 1, kstep = f & 1;
        int k = kstep * 32 + ((lane >> 4) << 3) + j;
        int n = ntile * 16 + (lane & 15);
        w1f[t] = (_Float16)w1[k * 64 + n];
    } else if (t < 10240) {
        int i = t - 4096;
        int f = i >> 9, lane = (i >> 3) & 63, j = i & 7;
        int ntile = f / 3, ks = f % 3;
        int n = ntile * 16 + (lane & 15);
        float v;
        if (ks < 2) {
            int k = ks * 32 + ((lane >> 4) << 3) + j;
            v = w_in[k * 64 + n];
        } else {
            v = ((lane >> 4) == 0 && j < 3) ? -w_in[(64 + j) * 64 + n] : 0.f;
        }
        wAf[i] = (_Float16)v;
    } else if (t < 13312) {
        int i = t - 10240;                      // d*1024 + ks*512 + lane*8 + j
        int d = i >> 10, ks = (i >> 9) & 1, lane = (i >> 3) & 63, j = i & 7;
        int k = ks * 32 + ((lane >> 4) << 3) + j;
        wpf[i] = (_Float16)w_in[(64 + d) * 64 + k];
    } else if (t < 13376) {
        int n = t - 13312;
        float s0 = 0.f, s1 = 0.f;
#pragma unroll
        for (int j = 0; j < 64; ++j) {
            s0 = fmaf(w2[n * 64 + j], w_out[j * 2 + 0], s0);
            s1 = fmaf(w2[n * 64 + j], w_out[j * 2 + 1], s1);
        }
        w0h[n] = (_Float16)s0;
        w1h[n] = (_Float16)s1;
    } else if (t < 13440) {
        int n = t - 13376;
        b1h[n] = (_Float16)b1[n];
    } else if (t == 13440) {
        float s0 = b_out[0], s1 = b_out[1];
#pragma unroll
        for (int j = 0; j < 64; ++j) {
            s0 = fmaf(b2[j], w_out[j * 2 + 0], s0);
            s1 = fmaf(b2[j], w_out[j * 2 + 1], s1);
        }
        bf[0] = s0; bf[1] = s1;
    }
}

// ---------------- prep: S table via MFMA -----------------------------------
__global__ __launch_bounds__(256) void precompute_S(
    const float* __restrict__ feats, const float* __restrict__ pcd,
    const float* __restrict__ b_in, const half8* __restrict__ wAf,
    _Float16* __restrict__ S, int N) {
    int lane = threadIdx.x & 63;
    int idx = lane & 15, g = lane >> 4;
    int base = (blockIdx.x * 4 + (threadIdx.x >> 6)) * 16;
    if (base >= N) return;

    half8 wa[12];
#pragma unroll
    for (int f = 0; f < 12; ++f) wa[f] = wAf[f * 64 + lane];

    int p = base + idx;
    int ps = p < N ? p : N - 1;
    const float4* fp = (const float4*)(feats + (size_t)ps * 64);
    float4 f0 = fp[2 * g], f1 = fp[2 * g + 1];
    float4 f2 = fp[8 + 2 * g], f3 = fp[8 + 2 * g + 1];
    half8 b0, b1v, b2v;
    b0[0]=(_Float16)f0.x; b0[1]=(_Float16)f0.y; b0[2]=(_Float16)f0.z; b0[3]=(_Float16)f0.w;
    b0[4]=(_Float16)f1.x; b0[5]=(_Float16)f1.y; b0[6]=(_Float16)f1.z; b0[7]=(_Float16)f1.w;
    b1v[0]=(_Float16)f2.x; b1v[1]=(_Float16)f2.y; b1v[2]=(_Float16)f2.z; b1v[3]=(_Float16)f2.w;
    b1v[4]=(_Float16)f3.x; b1v[5]=(_Float16)f3.y; b1v[6]=(_Float16)f3.z; b1v[7]=(_Float16)f3.w;
    float px = 0.f, py = 0.f, pz = 0.f;
    if (g == 0) {
        const float* pp = pcd + (size_t)ps * 3;
        px = pp[0]; py = pp[1]; pz = pp[2];
    }
#pragma unroll
    for (int i = 0; i < 8; ++i) b2v[i] = (_Float16)0.f;
    b2v[0] = (_Float16)px; b2v[1] = (_Float16)py; b2v[2] = (_Float16)pz;

#pragma unroll
    for (int tt = 0; tt < 4; ++tt) {
        f32x4 bi = *(const f32x4*)(b_in + tt * 16 + 4 * g);
        f32x4 acc;
        acc = __builtin_amdgcn_mfma_f32_16x16x32_f16(wa[tt * 3 + 0], b0, bi, 0, 0, 0);
        acc = __builtin_amdgcn_mfma_f32_16x16x32_f16(wa[tt * 3 + 1], b1v, acc, 0, 0, 0);
        acc = __builtin_amdgcn_mfma_f32_16x16x32_f16(wa[tt * 3 + 2], b2v, acc, 0, 0, 0);
        union { uint2 u; _Float16 h[4]; } o;
        o.h[0] = (_Float16)acc[0]; o.h[1] = (_Float16)acc[1];
        o.h[2] = (_Float16)acc[2]; o.h[3] = (_Float16)acc[3];
        if (p < N) *(uint2*)(S + (size_t)p * 64 + tt * 16 + 4 * g) = o.u;
    }
}

// ---------------- sort: histogram / scan / scatter -------------------------
__global__ __launch_bounds__(256) void hist_k(
    const int* __restrict__ col, int* __restrict__ cnt, int E) {
    int i = blockIdx.x * 256 + threadIdx.x;
    int stride = gridDim.x * 256;
    for (; i < E; i += stride) atomicAdd(&cnt[col[i]], 1);
}

// per-1024-bin tile: in-place exclusive scan, tile total -> part[b]
__global__ __launch_bounds__(256) void scan_local(
    int* __restrict__ cnt, int* __restrict__ part, int N) {
    __shared__ int s[256];
    int b = blockIdx.x, t = threadIdx.x;
    int base = b * 1024 + t * 4;
    int v[4];
    int sum = 0;
#pragma unroll
    for (int i = 0; i < 4; ++i) {
        int idx = base + i;
        v[i] = (idx < N) ? cnt[idx] : 0;
        sum += v[i];
    }
    s[t] = sum;
    __syncthreads();
    for (int off = 1; off < 256; off <<= 1) {
        int y = (t >= off) ? s[t - off] : 0;
        __syncthreads();
        s[t] += y;
        __syncthreads();
    }
    int run = s[t] - sum;     // exclusive prefix within tile
#pragma unroll
    for (int i = 0; i < 4; ++i) {
        int idx = base + i;
        int tmp = v[i];
        if (idx < N) cnt[idx] = run;
        run += tmp;
    }
    if (t == 255) part[b] = s[255];
}

__global__ void scan_part(int* part, int nb) {
    if (blockIdx.x == 0 && threadIdx.x == 0) {
        int run = 0;
        for (int i = 0; i < nb; ++i) {
            int t = part[i];
            part[i] = run;
            run += t;
        }
    }
}

__global__ __launch_bounds__(256) void scan_add(
    int* __restrict__ cnt, const int* __restrict__ part, int N) {
    int i = blockIdx.x * 256 + threadIdx.x;
    if (i < N) cnt[i] += part[i >> 10];
}

__global__ __launch_bounds__(256) void scatter_k(
    const int* __restrict__ row, const int* __restrict__ col,
    int* __restrict__ cnt, uint2* __restrict__ srt_rc,
    int* __restrict__ srt_e, int E, int Epad) {
    int i = blockIdx.x * 256 + threadIdx.x;
    if (i < E) {
        int c = col[i];
        int pos = atomicAdd(&cnt[c], 1);
        srt_rc[pos] = make_uint2((unsigned)row[i], (unsigned)c);
        srt_e[pos] = i;
    } else if (i < Epad) {
        srt_rc[i] = make_uint2(0u, 0u);
        srt_e[i] = 0x7fffffff;     // sentinel: no output write
    }
}

// ---------------- edge kernel (sorted stream) ------------------------------
__global__ __launch_bounds__(256) void edge_mfma(
    const _Float16* __restrict__ S, const float* __restrict__ also_pts,
    const uint2* __restrict__ srt_rc, const int* __restrict__ srt_e,
    const int* __restrict__ labels,
    const half8* __restrict__ w1f, const half8* __restrict__ wpf,
    const unsigned* __restrict__ w0p, const unsigned* __restrict__ w1p,
    const unsigned* __restrict__ b1p, const float* __restrict__ bfold,
    float* __restrict__ out, int E, int ngroups) {
    __shared__ half8 wf_lds[8][64];
    {
        int t = threadIdx.x;
        wf_lds[t >> 6][t & 63] = w1f[t];
        wf_lds[(t + 256) >> 6][t & 63] = w1f[t + 256];
    }
    __syncthreads();

    int lane = threadIdx.x & 63;
    int idx  = lane & 15;          // edge-in-group (D col)
    int g    = lane >> 4;
    int gwave  = blockIdx.x * 4 + (threadIdx.x >> 6);
    int nwaves = gridDim.x * 4;

    half8 wpd[3][2];
#pragma unroll
    for (int d = 0; d < 3; ++d)
#pragma unroll
        for (int ks = 0; ks < 2; ++ks) wpd[d][ks] = wpf[(d * 2 + ks) * 64 + lane];
    UPH w0v[8], w1v[8], b1v[8];
#pragma unroll
    for (int tt = 0; tt < 4; ++tt)
#pragma unroll
        for (int h = 0; h < 2; ++h) {
            int i = tt * 8 + 2 * g + h;
            w0v[tt * 2 + h].u = w0p[i];
            w1v[tt * 2 + h].u = w1p[i];
            b1v[tt * 2 + h].u = b1p[i];
        }
    float bfd = bfold[0] - bfold[1];
    half2v zero2 = {(_Float16)0.f, (_Float16)0.f};

    for (int grp = gwave; grp < ngroups; grp += nwaves) {
        int sb = (grp << 4) + idx;
        uint2 rc = srt_rc[sb];
        int eo = srt_e[sb];
        int r = (int)rc.x, c = (int)rc.y;

        // S gather: sorted c -> lanes mostly share rows (L1 broadcast)
        const uint4* sp = (const uint4*)(S + (size_t)c * 64);
        U84h s0u, s1u;
        s0u.u = sp[g];
        s1u.u = sp[4 + g];
        const float* ap = also_pts + (size_t)r * 3;
        float ax = ap[0], ay = ap[1], az = ap[2];
        int lb = labels[r];

        _Float16 ah = (_Float16)ax, bh = (_Float16)ay, ch = (_Float16)az;
        half8 av = {ah, ah, ah, ah, ah, ah, ah, ah};
        half8 bv = {bh, bh, bh, bh, bh, bh, bh, bh};
        half8 cv = {ch, ch, ch, ch, ch, ch, ch, ch};
        half8 q0 = av * wpd[0][0] + bv * wpd[1][0] + cv * wpd[2][0];
        half8 q1 = av * wpd[0][1] + bv * wpd[1][1] + cv * wpd[2][1];
        half8 x0 = relu8(s0u.h + q0);
        half8 x1 = relu8(s1u.h + q1);

        f32x4 zero = {0.f, 0.f, 0.f, 0.f};
        f32x4 acc[4];
#pragma unroll
        for (int tt = 0; tt < 4; ++tt) {
            acc[tt] = __builtin_amdgcn_mfma_f32_16x16x32_f16(wf_lds[2 * tt][lane],     x0, zero, 0, 0, 0);
            acc[tt] = __builtin_amdgcn_mfma_f32_16x16x32_f16(wf_lds[2 * tt + 1][lane], x1, acc[tt], 0, 0, 0);
        }

        half2v p0 = zero2, p1 = zero2;
#pragma unroll
        for (int tt = 0; tt < 4; ++tt) {
            half2v h01 = cvt2h(acc[tt][0], acc[tt][1]);
            half2v h23 = cvt2h(acc[tt][2], acc[tt][3]);
            h01 = __builtin_elementwise_max(h01 + b1v[tt * 2 + 0].h, zero2);
            h23 = __builtin_elementwise_max(h23 + b1v[tt * 2 + 1].h, zero2);
            p0 += h01 * w0v[tt * 2 + 0].h + h23 * w0v[tt * 2 + 1].h;
            p1 += h01 * w1v[tt * 2 + 0].h + h23 * w1v[tt * 2 + 1].h;
        }
        UPH P0, P1, T;
        P0.h = p0; P1.h = p1;
        T.i = __shfl_xor(P0.i, 16); P0.h += T.h;
        T.i = __shfl_xor(P0.i, 32); P0.h += T.h;
        T.i = __shfl_xor(P1.i, 16); P1.h += T.h;
        T.i = __shfl_xor(P1.i, 32); P1.h += T.h;

        if (g == 0 && eo < E) {
            float l0 = (float)P0.h[0] + (float)P0.h[1];
            float l1 = (float)P1.h[0] + (float)P1.h[1];
            float u = __expf(l1 - l0 - bfd);
            float pa = 1.f / (1.f + u);
            *(float2*)(out + (size_t)eo * 2) = make_float2(pa, 1.f - pa);
            out[(size_t)2 * E + eo] = (float)lb;
        }
    }
}

extern "C" void kernel_launch(void* const* d_in, const int* in_sizes, int n_in,
                              void* d_out, int out_size, void* d_ws, size_t ws_size,
                              hipStream_t stream) {
    const float* pcd      = (const float*)d_in[0];
    const float* feats    = (const float*)d_in[1];
    const float* also_pts = (const float*)d_in[2];
    const int*   labels   = (const int*)d_in[3];
    const int*   row      = (const int*)d_in[4];
    const int*   col      = (const int*)d_in[5];
    const float* w_in     = (const float*)d_in[6];
    const float* b_in     = (const float*)d_in[7];
    const float* w1       = (const float*)d_in[8];
    const float* b1       = (const float*)d_in[9];
    const float* w2       = (const float*)d_in[10];
    const float* b2       = (const float*)d_in[11];
    const float* w_out    = (const float*)d_in[12];
    const float* b_out    = (const float*)d_in[13];

    int N = in_sizes[0] / 3;
    int E = in_sizes[4];
    int Epad = (E + 15) & ~15;

    char* ws = (char*)d_ws;
    size_t off = 0;
    auto take = [&](size_t bytes) {
        char* p = ws + off;
        off = (off + bytes + 255) & ~(size_t)255;
        return p;
    };
    _Float16* Sb   = (_Float16*)take((size_t)N * 64 * 2);
    _Float16* w1f  = (_Float16*)take(4096 * 2);
    _Float16* wAf  = (_Float16*)take(6144 * 2);
    _Float16* wpf  = (_Float16*)take(3072 * 2);
    _Float16* w0h  = (_Float16*)take(64 * 2);
    _Float16* w1h  = (_Float16*)take(64 * 2);
    _Float16* b1h  = (_Float16*)take(64 * 2);
    float*    bf   = (float*)take(8);
    int*      cnt  = (int*)take((size_t)N * 4);
    int*      part = (int*)take(1024);
    uint2*    srt_rc = (uint2*)take((size_t)Epad * 8);
    int*      srt_e  = (int*)take((size_t)Epad * 4);

    pack_fold<<<53, 256, 0, stream>>>(w1, w_in, b1, w2, w_out, b2, b_out,
                                      w1f, wAf, wpf, w0h, w1h, b1h, bf);

    int ngroupsS = (N + 15) / 16;
    precompute_S<<<(ngroupsS + 3) / 4, 256, 0, stream>>>(
        feats, pcd, b_in, (const half8*)wAf, Sb, N);

    hipMemsetAsync(cnt, 0, (size_t)N * 4, stream);
    hist_k<<<1024, 256, 0, stream>>>(col, cnt, E);
    int nb = (N + 1023) >> 10;
    scan_local<<<nb, 256, 0, stream>>>(cnt, part, N);
    scan_part<<<1, 64, 0, stream>>>(part, nb);
    scan_add<<<(N + 255) / 256, 256, 0, stream>>>(cnt, part, N);
    scatter_k<<<(Epad + 255) / 256, 256, 0, stream>>>(row, col, cnt,
                                                      srt_rc, srt_e, E, Epad);

    int ngroups = Epad >> 4;
    edge_mfma<<<2048, 256, 0, stream>>>(Sb, also_pts, srt_rc, srt_e, labels,
                                        (const half8*)w1f, (const half8*)wpf,
                                        (const unsigned*)w0h, (const unsigned*)w1h,
                                        (const unsigned*)b1h, bf,
                                        (float*)d_out, E, ngroups);
}

// Round 14
// 200.985 us; speedup vs baseline: 1.7554x; 1.7554x over previous
//
#include <hip/hip_runtime.h>
#include <hip/hip_bf16.h>

// ---------------------------------------------------------------------------
// AlsoDecoder, folded + fp16 MFMA, LDS-resident constants for occupancy:
//   S[p] = feats[p]@W_f - pcd[p]@W_p + b_in   (MFMA prep kernel, fp16 table)
//   x1 = S[col] + also_pts[row]@W_p           (Q rebuilt per edge)
//   y  = relu(x1) @ W1                        (mfma 16x16x32 f16, swapped)
//   h2 = relu(y + b1)                         (packed-fp16 epilogue)
//   ldiff = h2 . wdiff ; probs = sigmoid(ldiff + bfd)   (layers 3+4 folded)
// All per-lane constants live in LDS; __launch_bounds__(256,6) caps regs.
// BUGFIX vs R12/R13: wpd_lds staging now covers ALL 384 entries (previous
// rounds wrote only 0..255 -> frags for the z coordinate were garbage LDS;
// that single bug explains both prior failures).
// ---------------------------------------------------------------------------

typedef _Float16 half8 __attribute__((ext_vector_type(8)));
typedef _Float16 half2v __attribute__((ext_vector_type(2)));
typedef __fp16   fp16x2 __attribute__((ext_vector_type(2)));
typedef __attribute__((ext_vector_type(4))) float f32x4;

union U84h { uint4 u; half8 h; };
union UPH  { half2v h; fp16x2 f; int i; unsigned u; };

__device__ __forceinline__ half2v cvt2h(float a, float b) {
    UPH t;
    t.f = __builtin_amdgcn_cvt_pkrtz(a, b);
    return t.h;
}

__device__ __forceinline__ half8 relu8(half8 v) {
    half8 z;
#pragma unroll
    for (int i = 0; i < 8; ++i) z[i] = (_Float16)0.f;
    return __builtin_elementwise_max(v, z);
}
__device__ __forceinline__ half8 splat8h(_Float16 h) {
    half8 r = {h, h, h, h, h, h, h, h};
    return r;
}

// ---------------- prep: pack weights --------------------------------------
__global__ __launch_bounds__(256) void pack_fold(
    const float* __restrict__ w1, const float* __restrict__ w_in,
    const float* __restrict__ b1, const float* __restrict__ w2,
    const float* __restrict__ w_out, const float* __restrict__ b2,
    const float* __restrict__ b_out,
    _Float16* __restrict__ w1f, _Float16* __restrict__ wAf,
    _Float16* __restrict__ wpf, _Float16* __restrict__ wdh,
    _Float16* __restrict__ b1h, float* __restrict__ bfd) {
    int t = blockIdx.x * 256 + threadIdx.x;
    if (t < 4096) {
        int f = t >> 9, lane = (t >> 3) & 63, j = t & 7;
        int ntile = f >> 1, kstep = f & 1;
        int k = kstep * 32 + ((lane >> 4) << 3) + j;
        int n = ntile * 16 + (lane & 15);
        w1f[t] = (_Float16)w1[k * 64 + n];
    } else if (t < 10240) {
        int i = t - 4096;
        int f = i >> 9, lane = (i >> 3) & 63, j = i & 7;
        int ntile = f / 3, ks = f % 3;
        int n = ntile * 16 + (lane & 15);
        float v;
        if (ks < 2) {
            int k = ks * 32 + ((lane >> 4) << 3) + j;
            v = w_in[k * 64 + n];
        } else {
            v = ((lane >> 4) == 0 && j < 3) ? -w_in[(64 + j) * 64 + n] : 0.f;
        }
        wAf[i] = (_Float16)v;
    } else if (t < 13312) {
        int i = t - 10240;                      // d*1024 + ks*512 + lane*8 + j
        int d = i >> 10, ks = (i >> 9) & 1, lane = (i >> 3) & 63, j = i & 7;
        int k = ks * 32 + ((lane >> 4) << 3) + j;
        wpf[i] = (_Float16)w_in[(64 + d) * 64 + k];
    } else if (t < 13376) {
        int n = t - 13312;
        float s = 0.f;
#pragma unroll
        for (int j = 0; j < 64; ++j)
            s = fmaf(w2[n * 64 + j], w_out[j * 2 + 0] - w_out[j * 2 + 1], s);
        wdh[n] = (_Float16)s;
    } else if (t < 13440) {
        int n = t - 13376;
        b1h[n] = (_Float16)b1[n];
    } else if (t == 13440) {
        float s = b_out[0] - b_out[1];
#pragma unroll
        for (int j = 0; j < 64; ++j)
            s = fmaf(b2[j], w_out[j * 2 + 0] - w_out[j * 2 + 1], s);
        bfd[0] = s;
    }
}

// ---------------- prep: S table via MFMA -----------------------------------
__global__ __launch_bounds__(256) void precompute_S(
    const float* __restrict__ feats, const float* __restrict__ pcd,
    const float* __restrict__ b_in, const half8* __restrict__ wAf,
    _Float16* __restrict__ S, int N) {
    int lane = threadIdx.x & 63;
    int idx = lane & 15, g = lane >> 4;
    int base = (blockIdx.x * 4 + (threadIdx.x >> 6)) * 16;
    if (base >= N) return;

    half8 wa[12];
#pragma unroll
    for (int f = 0; f < 12; ++f) wa[f] = wAf[f * 64 + lane];

    int p = base + idx;
    int ps = p < N ? p : N - 1;
    const float4* fp = (const float4*)(feats + (size_t)ps * 64);
    float4 f0 = fp[2 * g], f1 = fp[2 * g + 1];
    float4 f2 = fp[8 + 2 * g], f3 = fp[8 + 2 * g + 1];
    half8 b0, b1v, b2v;
    b0[0]=(_Float16)f0.x; b0[1]=(_Float16)f0.y; b0[2]=(_Float16)f0.z; b0[3]=(_Float16)f0.w;
    b0[4]=(_Float16)f1.x; b0[5]=(_Float16)f1.y; b0[6]=(_Float16)f1.z; b0[7]=(_Float16)f1.w;
    b1v[0]=(_Float16)f2.x; b1v[1]=(_Float16)f2.y; b1v[2]=(_Float16)f2.z; b1v[3]=(_Float16)f2.w;
    b1v[4]=(_Float16)f3.x; b1v[5]=(_Float16)f3.y; b1v[6]=(_Float16)f3.z; b1v[7]=(_Float16)f3.w;
    float px = 0.f, py = 0.f, pz = 0.f;
    if (g == 0) {
        const float* pp = pcd + (size_t)ps * 3;
        px = pp[0]; py = pp[1]; pz = pp[2];
    }
#pragma unroll
    for (int i = 0; i < 8; ++i) b2v[i] = (_Float16)0.f;
    b2v[0] = (_Float16)px; b2v[1] = (_Float16)py; b2v[2] = (_Float16)pz;

#pragma unroll
    for (int tt = 0; tt < 4; ++tt) {
        f32x4 bi = *(const f32x4*)(b_in + tt * 16 + 4 * g);
        f32x4 acc;
        acc = __builtin_amdgcn_mfma_f32_16x16x32_f16(wa[tt * 3 + 0], b0, bi, 0, 0, 0);
        acc = __builtin_amdgcn_mfma_f32_16x16x32_f16(wa[tt * 3 + 1], b1v, acc, 0, 0, 0);
        acc = __builtin_amdgcn_mfma_f32_16x16x32_f16(wa[tt * 3 + 2], b2v, acc, 0, 0, 0);
        union { uint2 u; _Float16 h[4]; } o;
        o.h[0] = (_Float16)acc[0]; o.h[1] = (_Float16)acc[1];
        o.h[2] = (_Float16)acc[2]; o.h[3] = (_Float16)acc[3];
        if (p < N) *(uint2*)(S + (size_t)p * 64 + tt * 16 + 4 * g) = o.u;
    }
}

// ---------------- edge kernel --------------------------------------------
__global__ __launch_bounds__(256, 6) void edge_mfma(
    const _Float16* __restrict__ S, const float* __restrict__ also_pts,
    const int* __restrict__ row, const int* __restrict__ col,
    const int* __restrict__ labels,
    const half8* __restrict__ w1f, const half8* __restrict__ wpf,
    const unsigned* __restrict__ wdp, const unsigned* __restrict__ b1p,
    const float* __restrict__ bfdp,
    float* __restrict__ out, int E, int ngroups) {
    __shared__ half8 wf_lds[8][64];     // W1 A-frags (512 half8)
    __shared__ half8 wpd_lds[6][64];    // W_p B-frags (384 half8)
    __shared__ unsigned wd_lds[32];     // packed fp16 pairs of wdiff
    __shared__ unsigned b1_lds[32];     // packed fp16 pairs of b1
    {
        int t = threadIdx.x;
        ((half8*)wf_lds)[t] = w1f[t];
        ((half8*)wf_lds)[t + 256] = w1f[t + 256];
        ((half8*)wpd_lds)[t] = wpf[t];                       // 0..255
        if (t < 128) ((half8*)wpd_lds)[t + 256] = wpf[t + 256]; // 256..383 (BUGFIX)
        if (t < 32) { wd_lds[t] = wdp[t]; b1_lds[t] = b1p[t]; }
    }
    __syncthreads();

    int lane = threadIdx.x & 63;
    int idx  = lane & 15;          // edge-in-group (D col)
    int g    = lane >> 4;
    float bfd = bfdp[0];
    half2v zero2 = {(_Float16)0.f, (_Float16)0.f};

    int gwave  = blockIdx.x * 4 + (threadIdx.x >> 6);
    int nwaves = gridDim.x * 4;

    for (int grp = gwave; grp < ngroups; grp += nwaves) {
        int e = (grp << 4) + idx;
        bool eok = e < E;
        int es = eok ? e : E - 1;
        int r = row[es], c = col[es];

        const uint4* sp = (const uint4*)(S + (size_t)c * 64);
        U84h s0u, s1u;
        s0u.u = sp[g];
        s1u.u = sp[4 + g];
        const float* ap = also_pts + (size_t)r * 3;
        float ax = ap[0], ay = ap[1], az = ap[2];
        int lb = labels[r];

        // Q rebuild from W_p frags (LDS)
        half8 av = splat8h((_Float16)ax);
        half8 bv = splat8h((_Float16)ay);
        half8 cv = splat8h((_Float16)az);
        half8 q0 = av * wpd_lds[0][lane] + bv * wpd_lds[2][lane] + cv * wpd_lds[4][lane];
        half8 q1 = av * wpd_lds[1][lane] + bv * wpd_lds[3][lane] + cv * wpd_lds[5][lane];
        half8 x0 = relu8(s0u.h + q0);
        half8 x1 = relu8(s1u.h + q1);

        // Y = W1'.X : lane holds Y[n=tt*16+4g+rr][edge=idx]
        f32x4 zero = {0.f, 0.f, 0.f, 0.f};
        f32x4 acc[4];
#pragma unroll
        for (int tt = 0; tt < 4; ++tt) {
            acc[tt] = __builtin_amdgcn_mfma_f32_16x16x32_f16(wf_lds[2 * tt][lane],     x0, zero, 0, 0, 0);
            acc[tt] = __builtin_amdgcn_mfma_f32_16x16x32_f16(wf_lds[2 * tt + 1][lane], x1, acc[tt], 0, 0, 0);
        }

        // packed fold: h2 = relu(y + b1); pd += h2 * wdiff
        half2v pd = zero2;
#pragma unroll
        for (int tt = 0; tt < 4; ++tt) {
            UPH b0u, b1u, w0u, w1u;
            int i0 = tt * 8 + 2 * g;
            b0u.u = b1_lds[i0];     b1u.u = b1_lds[i0 + 1];
            w0u.u = wd_lds[i0];     w1u.u = wd_lds[i0 + 1];
            half2v h01 = cvt2h(acc[tt][0], acc[tt][1]);
            half2v h23 = cvt2h(acc[tt][2], acc[tt][3]);
            h01 = __builtin_elementwise_max(h01 + b0u.h, zero2);
            h23 = __builtin_elementwise_max(h23 + b1u.h, zero2);
            pd += h01 * w0u.h + h23 * w1u.h;
        }
        UPH P, T;
        P.h = pd;
        T.i = __shfl_xor(P.i, 16); P.h += T.h;
        T.i = __shfl_xor(P.i, 32); P.h += T.h;

        if (g == 0 && eok) {
            float l = (float)P.h[0] + (float)P.h[1];   // l0 - l1 (no bias)
            float u = __expf(-(l + bfd));
            float pa = 1.f / (1.f + u);
            *(float2*)(out + (size_t)e * 2) = make_float2(pa, 1.f - pa);
            out[(size_t)2 * E + e] = (float)lb;
        }
    }
}

extern "C" void kernel_launch(void* const* d_in, const int* in_sizes, int n_in,
                              void* d_out, int out_size, void* d_ws, size_t ws_size,
                              hipStream_t stream) {
    const float* pcd      = (const float*)d_in[0];
    const float* feats    = (const float*)d_in[1];
    const float* also_pts = (const float*)d_in[2];
    const int*   labels   = (const int*)d_in[3];
    const int*   row      = (const int*)d_in[4];
    const int*   col      = (const int*)d_in[5];
    const float* w_in     = (const float*)d_in[6];
    const float* b_in     = (const float*)d_in[7];
    const float* w1       = (const float*)d_in[8];
    const float* b1       = (const float*)d_in[9];
    const float* w2       = (const float*)d_in[10];
    const float* b2       = (const float*)d_in[11];
    const float* w_out    = (const float*)d_in[12];
    const float* b_out    = (const float*)d_in[13];

    int N = in_sizes[0] / 3;
    int E = in_sizes[4];

    _Float16* Sb  = (_Float16*)d_ws;
    _Float16* w1f = Sb + (size_t)N * 64;
    _Float16* wAf = w1f + 4096;
    _Float16* wpf = wAf + 6144;
    _Float16* wdh = wpf + 3072;
    _Float16* b1h = wdh + 64;
    float*    bfd = (float*)(b1h + 64);

    pack_fold<<<53, 256, 0, stream>>>(w1, w_in, b1, w2, w_out, b2, b_out,
                                      w1f, wAf, wpf, wdh, b1h, bfd);

    int ngroupsS = (N + 15) / 16;
    precompute_S<<<(ngroupsS + 3) / 4, 256, 0, stream>>>(
        feats, pcd, b_in, (const half8*)wAf, Sb, N);

    int ngroups = (E + 15) / 16;
    edge_mfma<<<1536, 256, 0, stream>>>(Sb, also_pts, row, col, labels,
                                        (const half8*)w1f, (const half8*)wpf,
                                        (const unsigned*)wdh, (const unsigned*)b1h,
                                        bfd, (float*)d_out, E, ngroups);
}

// Round 15
// 77.635 us; speedup vs baseline: 4.5446x; 2.5888x over previous
//
#include <hip/hip_runtime.h>
#include <hip/hip_bf16.h>

// ---------------------------------------------------------------------------
// AlsoDecoder, folded + fp16 MFMA, fp8 S-table (halved gather traffic):
//   S8[p] = fp8_e4m3( feats[p]@W_f - pcd[p]@W_p + b_in )   (MFMA prep; row =
//           64B pre-packed in per-lane fragment byte order:
//           byte = g*16 + ks*8 + j  <->  feature n = ks*32 + 8g + j)
//   x1 = S8[col] (one 16B load/lane, fp8->f16) + also_pts[row]@W_p
//   y  = relu(x1) @ W1               (mfma 16x16x32 f16, swapped operands)
//   h2 = relu(y + b1);  ldiff = h2 . wdiff ;  probs = sigmoid(ldiff + bfd)
// Structure = R8 best-known (simple loop, reg constants, 35% occupancy) —
// R10/R14 proved both more ILP and more occupancy lose: the random gather
// trades latency vs L2-thrash traffic. Only byte reduction remains.
// ---------------------------------------------------------------------------

typedef _Float16 half8 __attribute__((ext_vector_type(8)));
typedef _Float16 half2v __attribute__((ext_vector_type(2)));
typedef __fp16   fp16x2 __attribute__((ext_vector_type(2)));
typedef __attribute__((ext_vector_type(4))) float f32x4;

union UPH  { half2v h; fp16x2 f; int i; unsigned u; };
union H8U  { half8 h; half2v p[4]; };

__device__ __forceinline__ half2v cvt2h(float a, float b) {
    UPH t;
    t.f = __builtin_amdgcn_cvt_pkrtz(a, b);
    return t.h;
}
// decode 2 fp8 (byte0,byte1 or byte2,byte3 of d) -> half2
__device__ __forceinline__ half2v fp8lo(unsigned d) {
    auto f = __builtin_amdgcn_cvt_pk_f32_fp8((int)d, false);
    return cvt2h(f[0], f[1]);
}
__device__ __forceinline__ half2v fp8hi(unsigned d) {
    auto f = __builtin_amdgcn_cvt_pk_f32_fp8((int)d, true);
    return cvt2h(f[0], f[1]);
}

__device__ __forceinline__ half8 relu8(half8 v) {
    half8 z;
#pragma unroll
    for (int i = 0; i < 8; ++i) z[i] = (_Float16)0.f;
    return __builtin_elementwise_max(v, z);
}
__device__ __forceinline__ half8 splat8h(_Float16 h) {
    half8 r = {h, h, h, h, h, h, h, h};
    return r;
}

// ---------------- prep: pack weights (verbatim from passed R14) ------------
__global__ __launch_bounds__(256) void pack_fold(
    const float* __restrict__ w1, const float* __restrict__ w_in,
    const float* __restrict__ b1, const float* __restrict__ w2,
    const float* __restrict__ w_out, const float* __restrict__ b2,
    const float* __restrict__ b_out,
    _Float16* __restrict__ w1f, _Float16* __restrict__ wAf,
    _Float16* __restrict__ wpf, _Float16* __restrict__ wdh,
    _Float16* __restrict__ b1h, float* __restrict__ bfd) {
    int t = blockIdx.x * 256 + threadIdx.x;
    if (t < 4096) {
        int f = t >> 9, lane = (t >> 3) & 63, j = t & 7;
        int ntile = f >> 1, kstep = f & 1;
        int k = kstep * 32 + ((lane >> 4) << 3) + j;
        int n = ntile * 16 + (lane & 15);
        w1f[t] = (_Float16)w1[k * 64 + n];
    } else if (t < 10240) {
        int i = t - 4096;
        int f = i >> 9, lane = (i >> 3) & 63, j = i & 7;
        int ntile = f / 3, ks = f % 3;
        int n = ntile * 16 + (lane & 15);
        float v;
        if (ks < 2) {
            int k = ks * 32 + ((lane >> 4) << 3) + j;
            v = w_in[k * 64 + n];
        } else {
            v = ((lane >> 4) == 0 && j < 3) ? -w_in[(64 + j) * 64 + n] : 0.f;
        }
        wAf[i] = (_Float16)v;
    } else if (t < 13312) {
        int i = t - 10240;                      // d*1024 + ks*512 + lane*8 + j
        int d = i >> 10, ks = (i >> 9) & 1, lane = (i >> 3) & 63, j = i & 7;
        int k = ks * 32 + ((lane >> 4) << 3) + j;
        wpf[i] = (_Float16)w_in[(64 + d) * 64 + k];
    } else if (t < 13376) {
        int n = t - 13312;
        float s = 0.f;
#pragma unroll
        for (int j = 0; j < 64; ++j)
            s = fmaf(w2[n * 64 + j], w_out[j * 2 + 0] - w_out[j * 2 + 1], s);
        wdh[n] = (_Float16)s;
    } else if (t < 13440) {
        int n = t - 13376;
        b1h[n] = (_Float16)b1[n];
    } else if (t == 13440) {
        float s = b_out[0] - b_out[1];
#pragma unroll
        for (int j = 0; j < 64; ++j)
            s = fmaf(b2[j], w_out[j * 2 + 0] - w_out[j * 2 + 1], s);
        bfd[0] = s;
    }
}

// ---------------- prep: S table via MFMA, fp8-packed output ----------------
// One wave per 16 points; C-init = b_in. Output row = 64B fp8, byte order
// byte(n) = (m>>3)*16 + ks*8 + (m&7)  with ks=n>>5, m=n&31.
__global__ __launch_bounds__(256) void precompute_S(
    const float* __restrict__ feats, const float* __restrict__ pcd,
    const float* __restrict__ b_in, const half8* __restrict__ wAf,
    unsigned char* __restrict__ S8, int N) {
    int lane = threadIdx.x & 63;
    int idx = lane & 15, g = lane >> 4;
    int base16 = (blockIdx.x * 4 + (threadIdx.x >> 6)) * 16;
    if (base16 >= N) return;

    half8 wa[12];
#pragma unroll
    for (int f = 0; f < 12; ++f) wa[f] = wAf[f * 64 + lane];

    int p = base16 + idx;
    int ps = p < N ? p : N - 1;
    const float4* fp = (const float4*)(feats + (size_t)ps * 64);
    float4 f0 = fp[2 * g], f1 = fp[2 * g + 1];
    float4 f2 = fp[8 + 2 * g], f3 = fp[8 + 2 * g + 1];
    half8 b0, b1v, b2v;
    b0[0]=(_Float16)f0.x; b0[1]=(_Float16)f0.y; b0[2]=(_Float16)f0.z; b0[3]=(_Float16)f0.w;
    b0[4]=(_Float16)f1.x; b0[5]=(_Float16)f1.y; b0[6]=(_Float16)f1.z; b0[7]=(_Float16)f1.w;
    b1v[0]=(_Float16)f2.x; b1v[1]=(_Float16)f2.y; b1v[2]=(_Float16)f2.z; b1v[3]=(_Float16)f2.w;
    b1v[4]=(_Float16)f3.x; b1v[5]=(_Float16)f3.y; b1v[6]=(_Float16)f3.z; b1v[7]=(_Float16)f3.w;
    float px = 0.f, py = 0.f, pz = 0.f;
    if (g == 0) {
        const float* pp = pcd + (size_t)ps * 3;
        px = pp[0]; py = pp[1]; pz = pp[2];
    }
#pragma unroll
    for (int i = 0; i < 8; ++i) b2v[i] = (_Float16)0.f;
    b2v[0] = (_Float16)px; b2v[1] = (_Float16)py; b2v[2] = (_Float16)pz;

#pragma unroll
    for (int tt = 0; tt < 4; ++tt) {
        f32x4 bi = *(const f32x4*)(b_in + tt * 16 + 4 * g);
        f32x4 acc;
        acc = __builtin_amdgcn_mfma_f32_16x16x32_f16(wa[tt * 3 + 0], b0, bi, 0, 0, 0);
        acc = __builtin_amdgcn_mfma_f32_16x16x32_f16(wa[tt * 3 + 1], b1v, acc, 0, 0, 0);
        acc = __builtin_amdgcn_mfma_f32_16x16x32_f16(wa[tt * 3 + 2], b2v, acc, 0, 0, 0);
        // pack 4 f32 -> 4 fp8 bytes (n = nb..nb+3)
        int u = __builtin_amdgcn_cvt_pk_fp8_f32(acc[0], acc[1], 0, false);
        u = __builtin_amdgcn_cvt_pk_fp8_f32(acc[2], acc[3], u, true);
        int nb = tt * 16 + 4 * g;
        int ks = nb >> 5, m = nb & 31;
        int byte_off = ((m >> 3) << 4) + (ks << 3) + (m & 7);
        if (p < N) *(int*)(S8 + (size_t)p * 64 + byte_off) = u;
    }
}

// ---------------- edge kernel --------------------------------------------
__global__ __launch_bounds__(256, 4) void edge_mfma(
    const unsigned char* __restrict__ S8, const float* __restrict__ also_pts,
    const int* __restrict__ row, const int* __restrict__ col,
    const int* __restrict__ labels,
    const half8* __restrict__ w1f, const half8* __restrict__ wpf,
    const unsigned* __restrict__ wdp, const unsigned* __restrict__ b1p,
    const float* __restrict__ bfdp,
    float* __restrict__ out, int E, int ngroups) {
    __shared__ half8 wf_lds[8][64];
    {
        int t = threadIdx.x;
        ((half8*)wf_lds)[t] = w1f[t];
        ((half8*)wf_lds)[t + 256] = w1f[t + 256];
    }
    __syncthreads();

    int lane = threadIdx.x & 63;
    int idx  = lane & 15;          // edge-in-group (D col)
    int g    = lane >> 4;
    int gwave  = blockIdx.x * 4 + (threadIdx.x >> 6);
    int nwaves = gridDim.x * 4;

    // persistent per-lane constants (registers — 35% occupancy is the sweet
    // spot per R10/R14; do NOT add streams or raise occupancy)
    half8 wpd[3][2];
#pragma unroll
    for (int d = 0; d < 3; ++d)
#pragma unroll
        for (int ks = 0; ks < 2; ++ks) wpd[d][ks] = wpf[(d * 2 + ks) * 64 + lane];
    UPH wdv[8], b1v[8];
#pragma unroll
    for (int tt = 0; tt < 4; ++tt)
#pragma unroll
        for (int h = 0; h < 2; ++h) {
            int i = tt * 8 + 2 * g + h;
            wdv[tt * 2 + h].u = wdp[i];
            b1v[tt * 2 + h].u = b1p[i];
        }
    float bfd = bfdp[0];
    half2v zero2 = {(_Float16)0.f, (_Float16)0.f};

    for (int grp = gwave; grp < ngroups; grp += nwaves) {
        int e = (grp << 4) + idx;
        bool eok = e < E;
        int es = eok ? e : E - 1;
        int r = row[es], c = col[es];

        // single 16B fp8 gather = both fragments of this lane
        uint4 sv = *(const uint4*)(S8 + (size_t)c * 64 + g * 16);
        const float* ap = also_pts + (size_t)r * 3;
        float ax = ap[0], ay = ap[1], az = ap[2];
        int lb = labels[r];

        // unpack fp8 -> f16
        H8U s0u, s1u;
        s0u.p[0] = fp8lo(sv.x); s0u.p[1] = fp8hi(sv.x);
        s0u.p[2] = fp8lo(sv.y); s0u.p[3] = fp8hi(sv.y);
        s1u.p[0] = fp8lo(sv.z); s1u.p[1] = fp8hi(sv.z);
        s1u.p[2] = fp8lo(sv.w); s1u.p[3] = fp8hi(sv.w);

        // Q rebuild (b_in already absorbed into S)
        half8 av = splat8h((_Float16)ax);
        half8 bv = splat8h((_Float16)ay);
        half8 cv = splat8h((_Float16)az);
        half8 q0 = av * wpd[0][0] + bv * wpd[1][0] + cv * wpd[2][0];
        half8 q1 = av * wpd[0][1] + bv * wpd[1][1] + cv * wpd[2][1];
        half8 x0 = relu8(s0u.h + q0);
        half8 x1 = relu8(s1u.h + q1);

        // Y = W1'.X : lane holds Y[n=tt*16+4g+rr][edge=idx]
        f32x4 zero = {0.f, 0.f, 0.f, 0.f};
        f32x4 acc[4];
#pragma unroll
        for (int tt = 0; tt < 4; ++tt) {
            acc[tt] = __builtin_amdgcn_mfma_f32_16x16x32_f16(wf_lds[2 * tt][lane],     x0, zero, 0, 0, 0);
            acc[tt] = __builtin_amdgcn_mfma_f32_16x16x32_f16(wf_lds[2 * tt + 1][lane], x1, acc[tt], 0, 0, 0);
        }

        // packed fold: h2 = relu(y + b1); pd += h2 * wdiff
        half2v pd = zero2;
#pragma unroll
        for (int tt = 0; tt < 4; ++tt) {
            half2v h01 = cvt2h(acc[tt][0], acc[tt][1]);
            half2v h23 = cvt2h(acc[tt][2], acc[tt][3]);
            h01 = __builtin_elementwise_max(h01 + b1v[tt * 2 + 0].h, zero2);
            h23 = __builtin_elementwise_max(h23 + b1v[tt * 2 + 1].h, zero2);
            pd += h01 * wdv[tt * 2 + 0].h + h23 * wdv[tt * 2 + 1].h;
        }
        UPH P, T;
        P.h = pd;
        T.i = __shfl_xor(P.i, 16); P.h += T.h;
        T.i = __shfl_xor(P.i, 32); P.h += T.h;

        if (g == 0 && eok) {
            float l = (float)P.h[0] + (float)P.h[1];   // l0 - l1 (no bias)
            float u = __expf(-(l + bfd));
            float pa = 1.f / (1.f + u);
            *(float2*)(out + (size_t)e * 2) = make_float2(pa, 1.f - pa);
            out[(size_t)2 * E + e] = (float)lb;
        }
    }
}

extern "C" void kernel_launch(void* const* d_in, const int* in_sizes, int n_in,
                              void* d_out, int out_size, void* d_ws, size_t ws_size,
                              hipStream_t stream) {
    const float* pcd      = (const float*)d_in[0];
    const float* feats    = (const float*)d_in[1];
    const float* also_pts = (const float*)d_in[2];
    const int*   labels   = (const int*)d_in[3];
    const int*   row      = (const int*)d_in[4];
    const int*   col      = (const int*)d_in[5];
    const float* w_in     = (const float*)d_in[6];
    const float* b_in     = (const float*)d_in[7];
    const float* w1       = (const float*)d_in[8];
    const float* b1       = (const float*)d_in[9];
    const float* w2       = (const float*)d_in[10];
    const float* b2       = (const float*)d_in[11];
    const float* w_out    = (const float*)d_in[12];
    const float* b_out    = (const float*)d_in[13];

    int N = in_sizes[0] / 3;
    int E = in_sizes[4];

    unsigned char* S8 = (unsigned char*)d_ws;                 // N*64 bytes
    _Float16* w1f = (_Float16*)(S8 + (size_t)N * 64);
    _Float16* wAf = w1f + 4096;
    _Float16* wpf = wAf + 6144;
    _Float16* wdh = wpf + 3072;
    _Float16* b1h = wdh + 64;
    float*    bfd = (float*)(b1h + 64);

    pack_fold<<<53, 256, 0, stream>>>(w1, w_in, b1, w2, w_out, b2, b_out,
                                      w1f, wAf, wpf, wdh, b1h, bfd);

    int ngroupsS = (N + 15) / 16;
    precompute_S<<<(ngroupsS + 3) / 4, 256, 0, stream>>>(
        feats, pcd, b_in, (const half8*)wAf, S8, N);

    int ngroups = (E + 15) / 16;
    edge_mfma<<<2048, 256, 0, stream>>>(S8, also_pts, row, col, labels,
                                        (const half8*)w1f, (const half8*)wpf,
                                        (const unsigned*)wdh, (const unsigned*)b1h,
                                        bfd, (float*)d_out, E, ngroups);
}